// Round 11
// baseline (92.711 us; speedup 1.0000x reference)
//
#include <hip/hip_runtime.h>

// ---------------------------------------------------------------------------
// DSTDGC R11.
// k0_stream: pure streaming x->xbf + m1/m2 projections (R10, proven ~18us).
// k1: RESTRUCTURED: block=(n, i-chunk of 4), 256 thr, grid 1024.
//     m2s in [j][k] stride-140 (conflict-free b128 reads -> 4 float4 LDS
//     reads per kt instead of 8 scalars), w_rm hoisted to VGPR once,
//     Ast gathers prefetched per jt ahead of the tanh block.
// k2: P = adj @ x then out = W_aug @ P per (n,t) (R10, ~roofline).
// ---------------------------------------------------------------------------

typedef float  f32x4  __attribute__((ext_vector_type(4)));
typedef short  bf16x8 __attribute__((ext_vector_type(8)));
typedef short  bf16x4 __attribute__((ext_vector_type(4)));

static __device__ __forceinline__ short f2bf(float f) {
    unsigned u = __float_as_uint(f);
    unsigned r = (u + 0x7FFFu + ((u >> 16) & 1u)) >> 16;   // RNE
    return (short)r;
}

static __device__ __forceinline__ bf16x8 cvt8f(const float4 a, const float4 b) {
    bf16x8 r;
    r[0] = f2bf(a.x); r[1] = f2bf(a.y); r[2] = f2bf(a.z); r[3] = f2bf(a.w);
    r[4] = f2bf(b.x); r[5] = f2bf(b.y); r[6] = f2bf(b.z); r[7] = f2bf(b.w);
    return r;
}

static __device__ __forceinline__ bf16x8 cvt8(const float* p) {
    return cvt8f(*(const float4*)p, *(const float4*)(p + 4));
}

// tanh(x) = 1 - 2/(exp(2x)+1)
static __device__ __forceinline__ float tanh_fast(float x) {
    float e = __expf(2.0f * x);
    return 1.0f - 2.0f * __builtin_amdgcn_rcpf(e + 1.0f);
}

static __device__ __forceinline__ float dot4(float4 a, float4 b) {
    return a.x * b.x + a.y * b.y + a.z * b.z + a.w * b.w;
}

#define MFMA16(a, b, c) __builtin_amdgcn_mfma_f32_16x16x32_bf16((a), (b), (c), 0, 0, 0)

// ---------------------------------------------------------------------------
// K0_stream: 8 threads per row (n,t,v).  Coalesced 16B in/out, no LDS.
// ---------------------------------------------------------------------------
__global__ __launch_bounds__(256) void k0_stream(
    const float* __restrict__ x,
    const float* __restrict__ w_m1, const float* __restrict__ b_m1,
    const float* __restrict__ w_m2, const float* __restrict__ b_m2,
    short* __restrict__ xbf, float* __restrict__ m1g, float* __restrict__ m2g)
{
    const int g  = blockIdx.x * 256 + threadIdx.x;
    const int R  = g >> 3;
    const int l8 = g & 7;
    const int c0 = l8 * 8;
    const int n  = R >> 12, tt = (R >> 6) & 63, v = R & 63;

    const float* xp = x + ((size_t)R << 6) + c0;
    const float4 a0 = *(const float4*)xp;
    const float4 a1 = *(const float4*)(xp + 4);

    float s0 = dot4(a0, *(const float4*)(w_m1 + c0))
             + dot4(a1, *(const float4*)(w_m1 + c0 + 4));
    float s1 = dot4(a0, *(const float4*)(w_m1 + 64 + c0))
             + dot4(a1, *(const float4*)(w_m1 + 64 + c0 + 4));
    float s2 = dot4(a0, *(const float4*)(w_m2 + c0))
             + dot4(a1, *(const float4*)(w_m2 + c0 + 4));
    float s3 = dot4(a0, *(const float4*)(w_m2 + 64 + c0))
             + dot4(a1, *(const float4*)(w_m2 + 64 + c0 + 4));

    *(bf16x8*)(xbf + ((size_t)R << 6) + c0) = cvt8f(a0, a1);

#pragma unroll
    for (int m = 1; m < 8; m <<= 1) {
        s0 += __shfl_xor(s0, m);
        s1 += __shfl_xor(s1, m);
        s2 += __shfl_xor(s2, m);
        s3 += __shfl_xor(s3, m);
    }
    if (l8 < 4) {
        float s    = (l8 == 0) ? s0 : (l8 == 1) ? s1 : (l8 == 2) ? s2 : s3;
        float bias = (l8 < 2) ? b_m1[l8] : b_m2[l8 - 2];
        float* base = (l8 < 2) ? m1g : m2g;
        base[n * 8192 + ((l8 & 1) * 64 + tt) * 64 + v] = s + bias;
    }
}

// ---------------------------------------------------------------------------
// K1: block (n, i-chunk of 4), 256 thr, grid 1024.  adjf[n,t,i,j] bf16.
// ---------------------------------------------------------------------------
__global__ __launch_bounds__(256) void k1_adj(
    const float* __restrict__ Ast,
    const float* __restrict__ w_rm, const float* __restrict__ b_rm,
    const float* __restrict__ m1g,  const float* __restrict__ m2g,
    const int* __restrict__ alpha_p,
    short* __restrict__ adjf)
{
    __shared__ float m2s[64 * 140];     // [j][k] stride 140 (35.8 KB)
    __shared__ float m1s[4 * 140];      // [iq][k]            (2.2 KB)

    const int wg = blockIdx.x;          // [n_hi(3)][ic(4)][n_lo(3)] XCD swizzle
    const int n  = (wg & 7) + ((wg >> 7) << 3);
    const int i0 = ((wg >> 3) & 15) * 4;
    const int tid = threadIdx.x;

    // stage m2[n]: global [k][j] float4 -> LDS [j][k] transpose
    const float4* src2 = (const float4*)(m2g + n * 8192);
    for (int it = tid; it < 2048; it += 256) {
        int k = it >> 4, j0 = (it & 15) * 4;
        float4 v = src2[it];
        m2s[(j0 + 0) * 140 + k] = v.x;
        m2s[(j0 + 1) * 140 + k] = v.y;
        m2s[(j0 + 2) * 140 + k] = v.z;
        m2s[(j0 + 3) * 140 + k] = v.w;
    }
    // stage m1 rows i0..i0+3: [k][i] -> [iq][k]
    if (tid < 128) {
        float4 v = *(const float4*)(m1g + n * 8192 + tid * 64 + i0);
        m1s[0 * 140 + tid] = v.x;
        m1s[1 * 140 + tid] = v.y;
        m1s[2 * 140 + tid] = v.z;
        m1s[3 * 140 + tid] = v.w;
    }
    __syncthreads();

    const int l = tid & 63, w = tid >> 6;
    const int lr = l & 15, lg = l >> 4;
    const int ig = i0 + w;

    float alpha;
    {
        int raw = alpha_p[0];
        unsigned ur = (unsigned)(raw < 0 ? -raw : raw);
        alpha = (ur < (1u << 23)) ? (float)raw : __int_as_float(raw);
    }

    // hoist w_rm B-fragments ONCE (16 L2 loads, 64 VGPR)
    bf16x8 afr[4][4];                   // [q][kt]
#pragma unroll
    for (int q = 0; q < 4; ++q)
#pragma unroll
        for (int kt = 0; kt < 4; ++kt)
            afr[q][kt] = cvt8(w_rm + (q * 16 + lr) * 128 + kt * 32 + lg * 8);
    float brm[4];
#pragma unroll
    for (int q = 0; q < 4; ++q) brm[q] = b_rm[q * 16 + lr];

    const float* m1row = m1s + w * 140;
    short* adjb = adjf + ((size_t)n << 18) + (ig << 6);

#pragma unroll 1
    for (int jt = 0; jt < 4; ++jt) {
        const int j0 = jt * 16 + lg * 4;

        // prefetch Ast gathers for all 4 q (overlaps the tanh block)
        float4 av[4];
#pragma unroll
        for (int q = 0; q < 4; ++q)
            av[q] = *(const float4*)(Ast + ((q * 16 + lr) << 12) + (ig << 6) + j0);

        // tanh A-fragments: vector LDS reads ([j][k] layout)
        const float* m2row = m2s + (jt * 16 + lr) * 140;
        bf16x8 bfr[4];
#pragma unroll
        for (int kt = 0; kt < 4; ++kt) {
            const int k0 = kt * 32 + lg * 8;
            float4 a0 = *(const float4*)(m1row + k0);
            float4 a1 = *(const float4*)(m1row + k0 + 4);
            float4 b0 = *(const float4*)(m2row + k0);
            float4 b1 = *(const float4*)(m2row + k0 + 4);
            bfr[kt][0] = f2bf(tanh_fast(a0.x - b0.x));
            bfr[kt][1] = f2bf(tanh_fast(a0.y - b0.y));
            bfr[kt][2] = f2bf(tanh_fast(a0.z - b0.z));
            bfr[kt][3] = f2bf(tanh_fast(a0.w - b0.w));
            bfr[kt][4] = f2bf(tanh_fast(a1.x - b1.x));
            bfr[kt][5] = f2bf(tanh_fast(a1.y - b1.y));
            bfr[kt][6] = f2bf(tanh_fast(a1.z - b1.z));
            bfr[kt][7] = f2bf(tanh_fast(a1.w - b1.w));
        }

#pragma unroll
        for (int q = 0; q < 4; ++q) {
            const int tq = q * 16 + lr;
            f32x4 acc = (f32x4){0.f, 0.f, 0.f, 0.f};
#pragma unroll
            for (int kt = 0; kt < 4; ++kt)
                acc = MFMA16(bfr[kt], afr[q][kt], acc);         // D[j][t]
            bf16x4 pv;
            pv[0] = f2bf(alpha * (acc[0] + brm[q]) + av[q].x);
            pv[1] = f2bf(alpha * (acc[1] + brm[q]) + av[q].y);
            pv[2] = f2bf(alpha * (acc[2] + brm[q]) + av[q].z);
            pv[3] = f2bf(alpha * (acc[3] + brm[q]) + av[q].w);
            *(bf16x4*)(adjb + ((size_t)tq << 12) + j0) = pv;    // 8B store
        }
    }
}

// ---------------------------------------------------------------------------
// K2: block = one (n,t), 4 waves.  P = adj @ x (ones-col -> rowsum), then
//     out = W_aug @ P with b_f as k=64 column.  float4 stores.
// ---------------------------------------------------------------------------
__global__ __launch_bounds__(256) void k2_out(
    const short* __restrict__ adjf, const short* __restrict__ xbf,
    const float* __restrict__ w_f,  const float* __restrict__ b_f,
    float* __restrict__ out)
{
    __shared__ short xT[64 * 72];       // [c][j] bf16, stride 72   (9.2 KB)
    __shared__ short P[64 * 104];       // [i][c] bf16, stride 104 (13.3 KB)

    const int pair = blockIdx.x;        // n*64 + t
    const int tid  = threadIdx.x;
    const int l = tid & 63, w = tid >> 6;
    const int lr = l & 15, lg = l >> 4;

    const short* Ab = adjf + ((size_t)pair << 12);
    const short* Xb = xbf  + ((size_t)pair << 12);
    float*       Ob = out  + ((size_t)pair << 12);

    bf16x8 adjA[4][2];
#pragma unroll
    for (int mt = 0; mt < 4; ++mt)
#pragma unroll
        for (int ks = 0; ks < 2; ++ks)
            adjA[mt][ks] = *(const bf16x8*)(Ab + (mt * 16 + lr) * 64
                                            + ks * 32 + lg * 8);

    {
        const int j  = tid >> 2;
        const int c0 = (tid & 3) * 16;
        bf16x8 r0 = *(const bf16x8*)(Xb + j * 64 + c0);
        bf16x8 r1 = *(const bf16x8*)(Xb + j * 64 + c0 + 8);
#pragma unroll
        for (int d = 0; d < 8; ++d) {
            xT[(c0 + d) * 72 + j]     = r0[d];
            xT[(c0 + 8 + d) * 72 + j] = r1[d];
        }
    }
    if (tid < 128) {
        int row = tid >> 1, cz = 80 + (tid & 1) * 8;
        bf16x8 z = {0, 0, 0, 0, 0, 0, 0, 0};
        *(bf16x8*)(P + row * 104 + cz) = z;
    }
    __syncthreads();

    {
        bf16x8 bx[2];
#pragma unroll
        for (int ks = 0; ks < 2; ++ks)
            bx[ks] = *(const bf16x8*)(xT + (w * 16 + lr) * 72 + ks * 32 + lg * 8);

        f32x4 acc[4];
#pragma unroll
        for (int mt = 0; mt < 4; ++mt) acc[mt] = (f32x4){0.f, 0.f, 0.f, 0.f};
#pragma unroll
        for (int ks = 0; ks < 2; ++ks)
#pragma unroll
            for (int mt = 0; mt < 4; ++mt)
                acc[mt] = MFMA16(adjA[mt][ks], bx[ks], acc[mt]);   // D[i][c]

#pragma unroll
        for (int mt = 0; mt < 4; ++mt)
#pragma unroll
            for (int e = 0; e < 4; ++e)
                P[(mt * 16 + lg * 4 + e) * 104 + w * 16 + lr] = f2bf(acc[mt][e]);

        if (w == 0) {
            bf16x8 ones = {0, 0, 0, 0, 0, 0, 0, 0};
            if (lr == 0) {
#pragma unroll
                for (int d = 0; d < 8; ++d) ones[d] = (short)0x3F80;
            }
            f32x4 accO[4];
#pragma unroll
            for (int mt = 0; mt < 4; ++mt) accO[mt] = (f32x4){0.f, 0.f, 0.f, 0.f};
#pragma unroll
            for (int ks = 0; ks < 2; ++ks)
#pragma unroll
                for (int mt = 0; mt < 4; ++mt)
                    accO[mt] = MFMA16(adjA[mt][ks], ones, accO[mt]);
#pragma unroll
            for (int mt = 0; mt < 4; ++mt)
#pragma unroll
                for (int e = 0; e < 4; ++e)
                    P[(mt * 16 + lg * 4 + e) * 104 + 64 + lr] = f2bf(accO[mt][e]);
        }
    }
    __syncthreads();

    {
        const int o = w * 16 + lr;
        bf16x8 afw[3];
#pragma unroll
        for (int ks = 0; ks < 2; ++ks)
            afw[ks] = cvt8(w_f + o * 64 + ks * 32 + lg * 8);
        {
            bf16x8 ab = {0, 0, 0, 0, 0, 0, 0, 0};
            if (lg == 0) ab[0] = f2bf(b_f[o]);      // Waug[o][64] = b_f[o]
            afw[2] = ab;
        }

#pragma unroll
        for (int nt = 0; nt < 4; ++nt) {
            const int i = nt * 16 + lr;
            bf16x8 bP[3];
#pragma unroll
            for (int ks = 0; ks < 3; ++ks)
                bP[ks] = *(const bf16x8*)(P + i * 104 + ks * 32 + lg * 8);
            f32x4 acc = (f32x4){0.f, 0.f, 0.f, 0.f};
#pragma unroll
            for (int ks = 0; ks < 3; ++ks)
                acc = MFMA16(afw[ks], bP[ks], acc);             // D[o][i]
            *(f32x4*)(Ob + i * 64 + w * 16 + lg * 4) = acc;
        }
    }
}

// ---------------------------------------------------------------------------
extern "C" void kernel_launch(void* const* d_in, const int* in_sizes, int n_in,
                              void* d_out, int out_size, void* d_ws, size_t ws_size,
                              hipStream_t stream)
{
    const float* x    = (const float*)d_in[0];
    const float* A    = (const float*)d_in[1];
    const float* w_m1 = (const float*)d_in[2];
    const float* b_m1 = (const float*)d_in[3];
    const float* w_m2 = (const float*)d_in[4];
    const float* b_m2 = (const float*)d_in[5];
    const float* w_rm = (const float*)d_in[6];
    const float* b_rm = (const float*)d_in[7];
    const float* w_f  = (const float*)d_in[8];
    const float* b_f  = (const float*)d_in[9];
    const int*   alpha = (const int*)d_in[10];

    char* ws = (char*)d_ws;
    float* m1g = (float*)(ws);                              // 2 MB  [n][k][i]
    float* m2g = (float*)(ws + (size_t)2 * 1024 * 1024);    // 2 MB  [n][k][j]
    short* xbf = (short*)(ws + (size_t)4 * 1024 * 1024);    // 32 MB [n][t][v][c]
    short* adjf = (short*)(ws + (size_t)4 * 1024 * 1024 + (size_t)33554432);
    float* out = (float*)d_out;

    k0_stream<<<dim3(8192), dim3(256), 0, stream>>>(x, w_m1, b_m1, w_m2, b_m2,
                                                    xbf, m1g, m2g);
    k1_adj<<<dim3(1024), dim3(256), 0, stream>>>(A, w_rm, b_rm, m1g, m2g,
                                                 alpha, adjf);
    k2_out<<<dim3(4096), dim3(256), 0, stream>>>(adjf, xbf, w_f, b_f, out);
}